// Round 3
// baseline (294.181 us; speedup 1.0000x reference)
//
#include <hip/hip_runtime.h>
#include <hip/hip_bf16.h>

// Reference analysis:
//   src_corr / H / SVD / det-branch are all DEAD: r is unconditionally
//   overwritten with eye(3) after the branch. Live outputs:
//     out[0..8]  = eye(3) row-major  -> {1,0,0, 0,1,0, 0,0,1}
//     out[9..11] = tb = -r @ src_mean = -mean(mkpts0, axis=1)   [3]
//   Only input read: mkpts0 [3, 8192] f32. valid_scores/mkpts1 untouched.

#define NPTS 8192

__global__ __launch_bounds__(256) void svdhead_kernel(
    const float* __restrict__ mkpts0, float* __restrict__ out) {
    const int row = blockIdx.x;        // 0..2, one block per row of mkpts0
    const int tid = threadIdx.x;       // 0..255

    // Sum row via float4 loads: 8192 floats = 2048 float4, 8 iters/thread.
    const float4* p = reinterpret_cast<const float4*>(mkpts0 + row * NPTS);
    float s = 0.0f;
    #pragma unroll
    for (int i = 0; i < 8; ++i) {
        float4 v = p[tid + i * 256];
        s += (v.x + v.y) + (v.z + v.w);
    }

    // Wave-64 shuffle reduction.
    #pragma unroll
    for (int off = 32; off > 0; off >>= 1) s += __shfl_down(s, off, 64);

    __shared__ float ws[4];
    const int lane = tid & 63;
    const int wid  = tid >> 6;
    if (lane == 0) ws[wid] = s;
    __syncthreads();

    if (tid == 0) {
        float tot = (ws[0] + ws[1]) + (ws[2] + ws[3]);
        out[9 + row] = -tot * (1.0f / (float)NPTS);
    }

    // Identity 3x3 (row-major): diagonal at flat indices 0,4,8.
    if (row == 0 && tid < 9) {
        out[tid] = ((tid & 3) == 0) ? 1.0f : 0.0f;
    }
}

extern "C" void kernel_launch(void* const* d_in, const int* in_sizes, int n_in,
                              void* d_out, int out_size, void* d_ws, size_t ws_size,
                              hipStream_t stream) {
    const float* mkpts0 = (const float*)d_in[0];   // [3, 8192]
    float* out = (float*)d_out;                    // 12 floats: r(9) + tb(3)
    svdhead_kernel<<<3, 256, 0, stream>>>(mkpts0, out);
}